// Round 1
// baseline (249.702 us; speedup 1.0000x reference)
//
#include <hip/hip_runtime.h>
#include <hip/hip_fp16.h>

// GCN 2-layer: N=50000 nodes, E=800000 edges, 128 -> 128(relu) -> 64
// R13: fused_agg_gemm gather restructured for latency (kernel was latency-
//      bound: 25% HBM, 33% VALU, 2% MFMA all simultaneously low).
//      (a) 32 edges/iter (was 16): 4 groups x 16 lanes, row read as 16x16B
//          float4 (same full-256B-row pattern; NOT the dead R4/R9 slicing).
//          Poisson(16) degrees + pad-to-32 => ~every block's max-degree wave
//          needed 2 serialized idx->gather roundtrip pairs; now 1.
//      (b) idx loads as 2x int4 (contiguous per group, 32B-aligned by the
//          pad-to-32 layout) instead of 8 scalar loads.
//      (c) __launch_bounds__(1024,8) caps VGPR at 64 -> 2 blocks/CU so GEMM
//          phase of one block overlaps gathers of the other.
//      (d) aggregate64: same int4 idx vectorization (structure unchanged).
// Evidence log: R2 MLP depth win; R4/R9 sliced layouts dead (instr cost /
// 128B-line thrash); flat gather 86.6MB compulsory (measured 80.9MB: no
// over-fetch left); R11 sentinel pad win; R12 fusion killed 51MB x2 trip;
// harness poison fills ~50us fixed, untouchable.

#define N_NODES 50000
#define N_EDGES 800000
#define BINW    128
#define NBIN    391                    // ceil(50000/128)
#define CAP     2560                   // mean bin load 2046, ~11 sigma margin
#define CAP2    6656                   // padded: up to 2560 + 128*31
#define B_CHUNK 2048
#define NB_SCAT ((N_EDGES + B_CHUNK - 1) / B_CHUNK)   // 391

typedef __bf16 bf16x8 __attribute__((ext_vector_type(8)));
typedef float  f32x4  __attribute__((ext_vector_type(4)));

// ---------------- prep: W-frags, zero gcur, zero sentinel rows ----------------
template<int N>
__device__ inline void wprep_body(const float* __restrict__ W,
                                  __bf16* __restrict__ hi, __bf16* __restrict__ lo,
                                  int idx) {
    if (idx >= (N / 16) * 4 * 64) return;
    int l = idx & 63;
    int s = (idx >> 6) & 3;
    int c = idx >> 8;
    int n = c * 16 + (l & 15);
    int k0 = s * 32 + (l >> 4) * 8;
#pragma unroll
    for (int j = 0; j < 8; j++) {
        float w = W[(k0 + j) * N + n];
        __bf16 h = (__bf16)w;
        hi[idx * 8 + j] = h;
        lo[idx * 8 + j] = (__bf16)(w - (float)h);
    }
}

__global__ __launch_bounds__(256) void prep_kernel(
        const float* __restrict__ W1, const float* __restrict__ W2,
        __bf16* __restrict__ w1hi, __bf16* __restrict__ w1lo,
        __bf16* __restrict__ w2hi, __bf16* __restrict__ w2lo,
        int* __restrict__ gcur, __half* __restrict__ hs1, __half* __restrict__ hs2) {
    int b = blockIdx.x, tid = threadIdx.x;
    if (b < 8)       wprep_body<128>(W1, w1hi, w1lo, b * 256 + tid);
    else if (b < 12) wprep_body<64> (W2, w2hi, w2lo, (b - 8) * 256 + tid);
    else {
        for (int i = tid; i < NBIN; i += 256) gcur[i] = 0;
        if (tid < 128) hs1[(size_t)N_NODES * 128 + tid] = __float2half(0.f);
        if (tid < 64)  hs2[(size_t)N_NODES * 64 + tid] = __float2half(0.f);
    }
}

// ---------------- bin_scatter: one edge pass -> per-bin packed (dst<<16|src) -------

__global__ __launch_bounds__(256) void bin_scatter_kernel(
        const int* __restrict__ src, const int* __restrict__ dst,
        int* __restrict__ gcur, unsigned* __restrict__ ebin) {
    __shared__ int cnt[512];
    __shared__ int boff[512];
    __shared__ int bcur[512];
    __shared__ int gbase[512];
    __shared__ unsigned stage[B_CHUNK];
    __shared__ int ex[256];
    int tid = threadIdx.x;
    int e0 = blockIdx.x * B_CHUNK;

    cnt[tid] = 0; cnt[tid + 256] = 0;
    __syncthreads();

    unsigned key[8]; int bins[8];
#pragma unroll
    for (int i = 0; i < 8; i++) {
        int e = e0 + tid + i * 256;               // coalesced
        if (e < N_EDGES) {
            int d = dst[e], s = src[e];
            key[i]  = ((unsigned)d << 16) | (unsigned)s;
            bins[i] = d >> 7;
            atomicAdd(&cnt[bins[i]], 1);
        } else bins[i] = -1;
    }
    __syncthreads();

    // exclusive scan of 512 bin counts with 256 threads (2 bins each)
    int a = cnt[2 * tid], b = cnt[2 * tid + 1];
    ex[tid] = a + b;
    __syncthreads();
    for (int off = 1; off < 256; off <<= 1) {
        int t = (tid >= off) ? ex[tid - off] : 0;
        __syncthreads();
        ex[tid] += t;
        __syncthreads();
    }
    int myex = ex[tid] - (a + b);
    boff[2 * tid] = myex;     boff[2 * tid + 1] = myex + a;
    bcur[2 * tid] = myex;     bcur[2 * tid + 1] = myex + a;
    __syncthreads();

    // compact into bin-contiguous staging
#pragma unroll
    for (int i = 0; i < 8; i++) {
        if (bins[i] >= 0) {
            int p = atomicAdd(&bcur[bins[i]], 1);
            stage[p] = key[i];
        }
    }

    // bulk-reserve global bin space (one atomic per non-empty (block,bin))
    __syncthreads();
    for (int b2 = tid; b2 < NBIN; b2 += 256) {
        int c = cnt[b2];
        gbase[b2] = (c > 0) ? atomicAdd(&gcur[b2], c) : 0;
    }
    __syncthreads();

    int total = N_EDGES - e0; if (total > B_CHUNK) total = B_CHUNK;
    for (int i = tid; i < total; i += 256) {
        unsigned k = stage[i];
        int bin = (int)(k >> 23);                 // dst>>7
        int idx = gbase[bin] + (i - boff[bin]);
        if (idx < CAP) ebin[(size_t)bin * CAP + idx] = k;  // guard (11-sigma)
    }
}

// ---------------- bin_build: histogram + padded scan + sentinel fill ---------------
__global__ __launch_bounds__(256) void bin_build_kernel(
        const unsigned* __restrict__ ebin, const int* __restrict__ gcur,
        int* __restrict__ deg, int* __restrict__ row_off,
        float* __restrict__ dinv, int* __restrict__ ssrc) {
    __shared__ int dl[BINW];
    __shared__ int pref[BINW];
    __shared__ int cur[BINW];
    __shared__ int padTotal;
    int bin = blockIdx.x, tid = threadIdx.x;
    if (tid < BINW) dl[tid] = 0;
    __syncthreads();
    int cnt = gcur[bin]; if (cnt > CAP) cnt = CAP;
    const unsigned* eb = ebin + (size_t)bin * CAP;
    for (int i = tid; i < cnt; i += 256)
        atomicAdd(&dl[(eb[i] >> 16) & 127], 1);
    __syncthreads();
    // Hillis-Steele inclusive scan over 128 PADDED counts
    int pc = 0;
    if (tid < BINW) { pc = (dl[tid] + 31) & ~31; pref[tid] = pc; }
    __syncthreads();
    for (int off = 1; off < BINW; off <<= 1) {
        int t = 0;
        if (tid < BINW && tid >= off) t = pref[tid - off];
        __syncthreads();
        if (tid < BINW) pref[tid] += t;
        __syncthreads();
    }
    if (tid < BINW) {
        int ex = pref[tid] - pc;                  // padded exclusive prefix
        cur[tid] = ex;
        int node = bin * BINW + tid;
        if (node < N_NODES) {
            deg[node]     = dl[tid];
            row_off[node] = bin * CAP2 + ex;
            dinv[node]    = rsqrtf((float)(dl[tid] + 1));   // +1 self-loop
        }
        if (tid == BINW - 1) padTotal = pref[tid];
    }
    __syncthreads();
    int pt = padTotal;
    int* sb = ssrc + (size_t)bin * CAP2;
    for (int i = tid; i < pt; i += 256) sb[i] = N_NODES;    // sentinel prefill
    __syncthreads();
    for (int i = tid; i < cnt; i += 256) {
        unsigned k = eb[i];
        int p = atomicAdd(&cur[(k >> 16) & 127], 1);
        sb[p] = (int)(k & 0xFFFFu);
    }
}

// ---------------- GEMM layer1: hs1[row][128] = fp16( dinv[row]*(X@W1)[row] ) ------
__global__ __launch_bounds__(256) void gemm_mfma128_kernel(
        const float* __restrict__ X, const __bf16* __restrict__ Whi,
        const __bf16* __restrict__ Wlo, const float* __restrict__ dinv,
        __half* __restrict__ hs) {
    constexpr int NC = 8;
    int tid = threadIdx.x;
    int w = tid >> 6, lane = tid & 63;
    int q = lane >> 4, lr = lane & 15;
    int rb = blockIdx.x * 64 + w * 16;
    int row = rb + lr;
    int rowc = (row < N_NODES) ? row : (N_NODES - 1);

    f32x4 acc[NC];
#pragma unroll
    for (int c = 0; c < NC; c++) acc[c] = (f32x4){0.f, 0.f, 0.f, 0.f};

#pragma unroll
    for (int s = 0; s < 4; s++) {
        const float* xp = X + (size_t)rowc * 128 + s * 32 + q * 8;
        float4 x0 = *(const float4*)xp;
        float4 x1 = *(const float4*)(xp + 4);
        float xv[8] = {x0.x, x0.y, x0.z, x0.w, x1.x, x1.y, x1.z, x1.w};
        bf16x8 a_hi, a_lo;
#pragma unroll
        for (int j = 0; j < 8; j++) {
            __bf16 h = (__bf16)xv[j];
            a_hi[j] = h;
            a_lo[j] = (__bf16)(xv[j] - (float)h);
        }
#pragma unroll
        for (int c = 0; c < NC; c++) {
            size_t fo = (size_t)((c * 4 + s) * 64 + lane) * 8;
            bf16x8 bh = *(const bf16x8*)(Whi + fo);
            bf16x8 bl = *(const bf16x8*)(Wlo + fo);
            acc[c] = __builtin_amdgcn_mfma_f32_16x16x32_bf16(a_hi, bh, acc[c], 0, 0, 0);
            acc[c] = __builtin_amdgcn_mfma_f32_16x16x32_bf16(a_lo, bh, acc[c], 0, 0, 0);
            acc[c] = __builtin_amdgcn_mfma_f32_16x16x32_bf16(a_hi, bl, acc[c], 0, 0, 0);
        }
    }

    // C/D layout: col = c*16 + lr, row(within 16) = q*4 + r
#pragma unroll
    for (int r = 0; r < 4; r++) {
        int grow = rb + q * 4 + r;
        if (grow < N_NODES) {
            float sc = dinv[grow];
#pragma unroll
            for (int c = 0; c < NC; c++) {
                hs[(size_t)grow * 128 + c * 16 + lr] = __float2half(acc[c][r] * sc);
            }
        }
    }
}

// ---------------- FUSED: agg128(+relu) -> LDS x2 rows -> 16x64 MFMA -> hs2 --------
// block = 1024 thr = 16 waves = 16 nodes (50000 = 3125*16 exact).
// R13 gather: 32 edges/iter. 4 groups of 16 lanes; group qt owns edges
// j+8*qt..j+8*qt+7 (contiguous -> 2x int4 idx loads, 32B-aligned by pad-32
// layout). Each row read as 16 lanes x float4 (full 256B line, 8 ch/lane).
// 8x dwordx4 gathers in flight per lane = 128B MLP; ~all nodes finish the
// gather in ONE idx->gather roundtrip pair (was 2 for d>16, i.e. the
// barrier-critical wave of nearly every block).
__global__ __launch_bounds__(1024, 8) void fused_agg_gemm_kernel(
        const __half* __restrict__ hs1, const int* __restrict__ row_off,
        const int* __restrict__ deg, const int* __restrict__ ssrc,
        const float* __restrict__ dinv, const float* __restrict__ bias,
        const __bf16* __restrict__ w2hi, const __bf16* __restrict__ w2lo,
        __half* __restrict__ hs2) {
    __shared__ float x2buf[16][132];              // pad 132: 2-way banks (free)
    int wave = threadIdx.x >> 6;
    int lane = threadIdx.x & 63;
    int rb = blockIdx.x * 16;
    int node = rb + wave;                         // always < N_NODES

    int beg = row_off[node];
    int d   = deg[node];
    float di = dinv[node];
    int qt = lane >> 4, sl = lane & 15;
    const float4* Hq = (const float4*)hs1;        // [N+1][16] 16B chunks
    float acc[8];
#pragma unroll
    for (int t = 0; t < 8; t++) acc[t] = 0.f;

    for (int j = 0; j < d; j += 32) {             // padded span, sentinel-safe
        const int* ip = ssrc + beg + j + 8 * qt;  // 16B-aligned (pad-32 layout)
        int4 i0 = *(const int4*)ip;
        int4 i1 = *(const int4*)(ip + 4);
        int s[8] = {i0.x, i0.y, i0.z, i0.w, i1.x, i1.y, i1.z, i1.w};
        float4 v[8];
#pragma unroll
        for (int u = 0; u < 8; u++) v[u] = Hq[(size_t)s[u] * 16 + sl];
#pragma unroll
        for (int u = 0; u < 8; u++) {
            const __half2* h2 = (const __half2*)&v[u];
#pragma unroll
            for (int t = 0; t < 4; t++) {
                float2 f = __half22float2(h2[t]);
                acc[2 * t]     += f.x;
                acc[2 * t + 1] += f.y;
            }
        }
    }
    // reduce across the 4 edge-groups: lanes {sl, sl+16, sl+32, sl+48}
#pragma unroll
    for (int t = 0; t < 8; t++) {
        acc[t] += __shfl_xor(acc[t], 16, 64);
        acc[t] += __shfl_xor(acc[t], 32, 64);
    }
    if (qt == 0) {
        float4 sv = Hq[(size_t)node * 16 + sl];   // self-loop (8 halves)
        const __half2* h2 = (const __half2*)&sv;
        float4 b0 = ((const float4*)bias)[2 * sl];
        float4 b1 = ((const float4*)bias)[2 * sl + 1];
        float2 f0 = __half22float2(h2[0]);
        float2 f1 = __half22float2(h2[1]);
        float2 f2 = __half22float2(h2[2]);
        float2 f3 = __half22float2(h2[3]);
        float4 o0, o1;
        o0.x = fmaxf(fmaf(di, acc[0] + f0.x, b0.x), 0.f);     // relu
        o0.y = fmaxf(fmaf(di, acc[1] + f0.y, b0.y), 0.f);
        o0.z = fmaxf(fmaf(di, acc[2] + f1.x, b0.z), 0.f);
        o0.w = fmaxf(fmaf(di, acc[3] + f1.y, b0.w), 0.f);
        o1.x = fmaxf(fmaf(di, acc[4] + f2.x, b1.x), 0.f);
        o1.y = fmaxf(fmaf(di, acc[5] + f2.y, b1.y), 0.f);
        o1.z = fmaxf(fmaf(di, acc[6] + f3.x, b1.z), 0.f);
        o1.w = fmaxf(fmaf(di, acc[7] + f3.y, b1.w), 0.f);
        *(float4*)&x2buf[wave][8 * sl]     = o0;
        *(float4*)&x2buf[wave][8 * sl + 4] = o1;
    }
    __syncthreads();

    // GEMM phase: waves 0-3, wave = col-frag c (16 cols each)
    if (threadIdx.x < 256) {
        int c = wave;
        int q = lane >> 4, lr = lane & 15;
        f32x4 g = (f32x4){0.f, 0.f, 0.f, 0.f};
#pragma unroll
        for (int s = 0; s < 4; s++) {
            const float* xp = &x2buf[lr][s * 32 + q * 8];
            float4 a0 = *(const float4*)xp;
            float4 a1 = *(const float4*)(xp + 4);
            float xv[8] = {a0.x, a0.y, a0.z, a0.w, a1.x, a1.y, a1.z, a1.w};
            bf16x8 a_hi, a_lo;
#pragma unroll
            for (int j = 0; j < 8; j++) {
                __bf16 h = (__bf16)xv[j];
                a_hi[j] = h;
                a_lo[j] = (__bf16)(xv[j] - (float)h);
            }
            size_t fo = (size_t)((c * 4 + s) * 64 + lane) * 8;
            bf16x8 bh = *(const bf16x8*)(w2hi + fo);
            bf16x8 bl = *(const bf16x8*)(w2lo + fo);
            g = __builtin_amdgcn_mfma_f32_16x16x32_bf16(a_hi, bh, g, 0, 0, 0);
            g = __builtin_amdgcn_mfma_f32_16x16x32_bf16(a_lo, bh, g, 0, 0, 0);
            g = __builtin_amdgcn_mfma_f32_16x16x32_bf16(a_hi, bl, g, 0, 0, 0);
        }
#pragma unroll
        for (int r = 0; r < 4; r++) {
            int grow = rb + q * 4 + r;
            hs2[(size_t)grow * 64 + c * 16 + lr] = __float2half(g[r] * dinv[grow]);
        }
    }
}

// ---------------- Aggregate CH=64: wave/node, 8B/lane = 4 rows/instr --------------
// R13: idx loads vectorized to 2x int4 per group (contiguous edge chunks).
__global__ __launch_bounds__(256) void aggregate64_kernel(
        const __half* __restrict__ hs, const int* __restrict__ row_off,
        const int* __restrict__ deg, const int* __restrict__ ssrc,
        const float* __restrict__ dinv, const float* __restrict__ bias,
        float* __restrict__ out) {
    int node = (blockIdx.x * 256 + threadIdx.x) >> 6;
    int lane = threadIdx.x & 63;
    if (node >= N_NODES) return;
    int beg = row_off[node];
    int d   = deg[node];
    float di = dinv[node];
    int qt = lane >> 4, sl = lane & 15;
    const float2* Hq = (const float2*)hs;        // [N+1][16] 8B chunks
    float4 acc = make_float4(0.f, 0.f, 0.f, 0.f);
    for (int j = 0; j < d; j += 32) {            // padded span, sentinel-safe
        const int* ip = ssrc + beg + j + 8 * qt; // 16B-aligned (pad-32 layout)
        int4 i0 = *(const int4*)ip;
        int4 i1 = *(const int4*)(ip + 4);
        int s[8] = {i0.x, i0.y, i0.z, i0.w, i1.x, i1.y, i1.z, i1.w};
        float2 v[8];
#pragma unroll
        for (int u = 0; u < 8; u++) v[u] = Hq[(size_t)s[u] * 16 + sl];
#pragma unroll
        for (int u = 0; u < 8; u++) {
            float2 f0 = __half22float2(((const __half2*)&v[u])[0]);
            float2 f1 = __half22float2(((const __half2*)&v[u])[1]);
            acc.x += f0.x; acc.y += f0.y; acc.z += f1.x; acc.w += f1.y;
        }
    }
    acc.x += __shfl_xor(acc.x, 16, 64);
    acc.y += __shfl_xor(acc.y, 16, 64);
    acc.z += __shfl_xor(acc.z, 16, 64);
    acc.w += __shfl_xor(acc.w, 16, 64);
    acc.x += __shfl_xor(acc.x, 32, 64);
    acc.y += __shfl_xor(acc.y, 32, 64);
    acc.z += __shfl_xor(acc.z, 32, 64);
    acc.w += __shfl_xor(acc.w, 32, 64);
    if (lane < 16) {
        float2 sv = Hq[(size_t)node * 16 + sl];  // self-loop
        float2 f0 = __half22float2(((const __half2*)&sv)[0]);
        float2 f1 = __half22float2(((const __half2*)&sv)[1]);
        float4 b = ((const float4*)bias)[sl];
        float4 o;
        o.x = fmaf(di, acc.x + f0.x, b.x);
        o.y = fmaf(di, acc.y + f0.y, b.y);
        o.z = fmaf(di, acc.z + f1.x, b.z);
        o.w = fmaf(di, acc.w + f1.y, b.w);
        ((float4*)out)[(size_t)node * 16 + sl] = o;
    }
}

// ---------------- launch ----------------

extern "C" void kernel_launch(void* const* d_in, const int* in_sizes, int n_in,
                              void* d_out, int out_size, void* d_ws, size_t ws_size,
                              hipStream_t stream) {
    const float* x  = (const float*)d_in[0];   // [N,128]
    const int*   ei = (const int*)d_in[1];     // [2,E]
    const float* W1 = (const float*)d_in[2];   // [128,128]
    const float* b1 = (const float*)d_in[3];   // [128]
    const float* W2 = (const float*)d_in[4];   // [128,64]
    const float* b2 = (const float*)d_in[5];   // [64]
    float* out = (float*)d_out;                // [N,64]

    const int* src = ei;
    const int* dst = ei + N_EDGES;

    char* p = (char*)d_ws;
    size_t off = 0;
    auto alloc = [&](size_t bytes) { void* q = p + off; off += (bytes + 255) & ~(size_t)255; return q; };
    float*    dinv    = (float*)   alloc(N_NODES * 4);
    int*      deg     = (int*)     alloc(N_NODES * 4);
    int*      row_off = (int*)     alloc(N_NODES * 4);
    int*      gcur    = (int*)     alloc(NBIN * 4);
    int*      ssrc    = (int*)     alloc((size_t)NBIN * CAP2 * 4);  // 10.4 MB
    unsigned* ebin    = (unsigned*)alloc((size_t)NBIN * CAP * 4);   // 4.0 MB
    __bf16*   w1hi    = (__bf16*)  alloc(128 * 128 * 2);
    __bf16*   w1lo    = (__bf16*)  alloc(128 * 128 * 2);
    __bf16*   w2hi    = (__bf16*)  alloc(128 * 64 * 2);
    __bf16*   w2lo    = (__bf16*)  alloc(128 * 64 * 2);
    __half*   hs1     = (__half*)  alloc((size_t)(N_NODES + 1) * 128 * 2);
    __half*   hs2     = (__half*)  alloc((size_t)(N_NODES + 1) * 64 * 2);

    // 6 launches total
    prep_kernel<<<13, 256, 0, stream>>>(W1, W2, w1hi, w1lo, w2hi, w2lo, gcur, hs1, hs2);
    bin_scatter_kernel<<<NB_SCAT, 256, 0, stream>>>(src, dst, gcur, ebin);
    bin_build_kernel<<<NBIN, 256, 0, stream>>>(ebin, gcur, deg, row_off, dinv, ssrc);

    gemm_mfma128_kernel<<<(N_NODES + 63) / 64, 256, 0, stream>>>(x, w1hi, w1lo, dinv, hs1);
    fused_agg_gemm_kernel<<<N_NODES / 16, 1024, 0, stream>>>(
        hs1, row_off, deg, ssrc, dinv, b1, w2hi, w2lo, hs2);
    aggregate64_kernel<<<(N_NODES * 64 + 255) / 256, 256, 0, stream>>>(
        hs2, row_off, deg, ssrc, dinv, b2, out);
}

// Round 2
// 195.426 us; speedup vs baseline: 1.2777x; 1.2777x over previous
//
#include <hip/hip_runtime.h>
#include <hip/hip_fp16.h>

// GCN 2-layer: N=50000 nodes, E=800000 edges, 128 -> 128(relu) -> 64
// R14: R13 post-mortem: WRITE_SIZE 6.25->268.8MB = scratch spills. The
//      launch_bounds(1024,8) VGPR cap (64) + float4 v[8] (32 regs) forced the
//      gather buffers into scratch -> 2.5x regression. REVERTED to R12 gather
//      shape (float2, 16 edges/iter, no min-waves bound). New latency attack,
//      register-neutral:
//      (a) idx loads: ONE coalesced ssrc load per 64 edges (s_all, 1 VGPR) +
//          __shfl broadcast, replacing 8 scalar loads/iter. Removes the
//          idx->gather serialization from every iteration (idx latency paid
//          once per node, not per 16 edges).
//      (b) gather double-buffer v[8]/w[8] (16+16 regs): iter n+1's gathers
//          issue before iter n's accumulate -> gather roundtrips overlap.
//          Critical path: k*(idx+gather) -> idx + gather + k*accum.
//      (c) same restructure in aggregate64.
// Evidence log: R2 MLP depth win; R4/R9 sliced layouts dead; flat gather
// 86.6MB compulsory (measured 80.9MB); R11 sentinel pad win; R12 fusion
// killed 51MB x2 trip; R13 spill catastrophe (never combine min-waves cap
// with fatter per-lane buffers); harness poison fills ~50us fixed.

#define N_NODES 50000
#define N_EDGES 800000
#define BINW    128
#define NBIN    391                    // ceil(50000/128)
#define CAP     2560                   // mean bin load 2046, ~11 sigma margin
#define CAP2    6656                   // padded: up to 2560 + 128*31
#define B_CHUNK 2048
#define NB_SCAT ((N_EDGES + B_CHUNK - 1) / B_CHUNK)   // 391

typedef __bf16 bf16x8 __attribute__((ext_vector_type(8)));
typedef float  f32x4  __attribute__((ext_vector_type(4)));

// ---------------- prep: W-frags, zero gcur, zero sentinel rows ----------------
template<int N>
__device__ inline void wprep_body(const float* __restrict__ W,
                                  __bf16* __restrict__ hi, __bf16* __restrict__ lo,
                                  int idx) {
    if (idx >= (N / 16) * 4 * 64) return;
    int l = idx & 63;
    int s = (idx >> 6) & 3;
    int c = idx >> 8;
    int n = c * 16 + (l & 15);
    int k0 = s * 32 + (l >> 4) * 8;
#pragma unroll
    for (int j = 0; j < 8; j++) {
        float w = W[(k0 + j) * N + n];
        __bf16 h = (__bf16)w;
        hi[idx * 8 + j] = h;
        lo[idx * 8 + j] = (__bf16)(w - (float)h);
    }
}

__global__ __launch_bounds__(256) void prep_kernel(
        const float* __restrict__ W1, const float* __restrict__ W2,
        __bf16* __restrict__ w1hi, __bf16* __restrict__ w1lo,
        __bf16* __restrict__ w2hi, __bf16* __restrict__ w2lo,
        int* __restrict__ gcur, __half* __restrict__ hs1, __half* __restrict__ hs2) {
    int b = blockIdx.x, tid = threadIdx.x;
    if (b < 8)       wprep_body<128>(W1, w1hi, w1lo, b * 256 + tid);
    else if (b < 12) wprep_body<64> (W2, w2hi, w2lo, (b - 8) * 256 + tid);
    else {
        for (int i = tid; i < NBIN; i += 256) gcur[i] = 0;
        if (tid < 128) hs1[(size_t)N_NODES * 128 + tid] = __float2half(0.f);
        if (tid < 64)  hs2[(size_t)N_NODES * 64 + tid] = __float2half(0.f);
    }
}

// ---------------- bin_scatter: one edge pass -> per-bin packed (dst<<16|src) -------

__global__ __launch_bounds__(256) void bin_scatter_kernel(
        const int* __restrict__ src, const int* __restrict__ dst,
        int* __restrict__ gcur, unsigned* __restrict__ ebin) {
    __shared__ int cnt[512];
    __shared__ int boff[512];
    __shared__ int bcur[512];
    __shared__ int gbase[512];
    __shared__ unsigned stage[B_CHUNK];
    __shared__ int ex[256];
    int tid = threadIdx.x;
    int e0 = blockIdx.x * B_CHUNK;

    cnt[tid] = 0; cnt[tid + 256] = 0;
    __syncthreads();

    unsigned key[8]; int bins[8];
#pragma unroll
    for (int i = 0; i < 8; i++) {
        int e = e0 + tid + i * 256;               // coalesced
        if (e < N_EDGES) {
            int d = dst[e], s = src[e];
            key[i]  = ((unsigned)d << 16) | (unsigned)s;
            bins[i] = d >> 7;
            atomicAdd(&cnt[bins[i]], 1);
        } else bins[i] = -1;
    }
    __syncthreads();

    // exclusive scan of 512 bin counts with 256 threads (2 bins each)
    int a = cnt[2 * tid], b = cnt[2 * tid + 1];
    ex[tid] = a + b;
    __syncthreads();
    for (int off = 1; off < 256; off <<= 1) {
        int t = (tid >= off) ? ex[tid - off] : 0;
        __syncthreads();
        ex[tid] += t;
        __syncthreads();
    }
    int myex = ex[tid] - (a + b);
    boff[2 * tid] = myex;     boff[2 * tid + 1] = myex + a;
    bcur[2 * tid] = myex;     bcur[2 * tid + 1] = myex + a;
    __syncthreads();

    // compact into bin-contiguous staging
#pragma unroll
    for (int i = 0; i < 8; i++) {
        if (bins[i] >= 0) {
            int p = atomicAdd(&bcur[bins[i]], 1);
            stage[p] = key[i];
        }
    }

    // bulk-reserve global bin space (one atomic per non-empty (block,bin))
    __syncthreads();
    for (int b2 = tid; b2 < NBIN; b2 += 256) {
        int c = cnt[b2];
        gbase[b2] = (c > 0) ? atomicAdd(&gcur[b2], c) : 0;
    }
    __syncthreads();

    int total = N_EDGES - e0; if (total > B_CHUNK) total = B_CHUNK;
    for (int i = tid; i < total; i += 256) {
        unsigned k = stage[i];
        int bin = (int)(k >> 23);                 // dst>>7
        int idx = gbase[bin] + (i - boff[bin]);
        if (idx < CAP) ebin[(size_t)bin * CAP + idx] = k;  // guard (11-sigma)
    }
}

// ---------------- bin_build: histogram + padded scan + sentinel fill ---------------
__global__ __launch_bounds__(256) void bin_build_kernel(
        const unsigned* __restrict__ ebin, const int* __restrict__ gcur,
        int* __restrict__ deg, int* __restrict__ row_off,
        float* __restrict__ dinv, int* __restrict__ ssrc) {
    __shared__ int dl[BINW];
    __shared__ int pref[BINW];
    __shared__ int cur[BINW];
    __shared__ int padTotal;
    int bin = blockIdx.x, tid = threadIdx.x;
    if (tid < BINW) dl[tid] = 0;
    __syncthreads();
    int cnt = gcur[bin]; if (cnt > CAP) cnt = CAP;
    const unsigned* eb = ebin + (size_t)bin * CAP;
    for (int i = tid; i < cnt; i += 256)
        atomicAdd(&dl[(eb[i] >> 16) & 127], 1);
    __syncthreads();
    // Hillis-Steele inclusive scan over 128 PADDED counts
    int pc = 0;
    if (tid < BINW) { pc = (dl[tid] + 31) & ~31; pref[tid] = pc; }
    __syncthreads();
    for (int off = 1; off < BINW; off <<= 1) {
        int t = 0;
        if (tid < BINW && tid >= off) t = pref[tid - off];
        __syncthreads();
        if (tid < BINW) pref[tid] += t;
        __syncthreads();
    }
    if (tid < BINW) {
        int ex = pref[tid] - pc;                  // padded exclusive prefix
        cur[tid] = ex;
        int node = bin * BINW + tid;
        if (node < N_NODES) {
            deg[node]     = dl[tid];
            row_off[node] = bin * CAP2 + ex;
            dinv[node]    = rsqrtf((float)(dl[tid] + 1));   // +1 self-loop
        }
        if (tid == BINW - 1) padTotal = pref[tid];
    }
    __syncthreads();
    int pt = padTotal;
    int* sb = ssrc + (size_t)bin * CAP2;
    for (int i = tid; i < pt; i += 256) sb[i] = N_NODES;    // sentinel prefill
    __syncthreads();
    for (int i = tid; i < cnt; i += 256) {
        unsigned k = eb[i];
        int p = atomicAdd(&cur[(k >> 16) & 127], 1);
        sb[p] = (int)(k & 0xFFFFu);
    }
}

// ---------------- GEMM layer1: hs1[row][128] = fp16( dinv[row]*(X@W1)[row] ) ------
__global__ __launch_bounds__(256) void gemm_mfma128_kernel(
        const float* __restrict__ X, const __bf16* __restrict__ Whi,
        const __bf16* __restrict__ Wlo, const float* __restrict__ dinv,
        __half* __restrict__ hs) {
    constexpr int NC = 8;
    int tid = threadIdx.x;
    int w = tid >> 6, lane = tid & 63;
    int q = lane >> 4, lr = lane & 15;
    int rb = blockIdx.x * 64 + w * 16;
    int row = rb + lr;
    int rowc = (row < N_NODES) ? row : (N_NODES - 1);

    f32x4 acc[NC];
#pragma unroll
    for (int c = 0; c < NC; c++) acc[c] = (f32x4){0.f, 0.f, 0.f, 0.f};

#pragma unroll
    for (int s = 0; s < 4; s++) {
        const float* xp = X + (size_t)rowc * 128 + s * 32 + q * 8;
        float4 x0 = *(const float4*)xp;
        float4 x1 = *(const float4*)(xp + 4);
        float xv[8] = {x0.x, x0.y, x0.z, x0.w, x1.x, x1.y, x1.z, x1.w};
        bf16x8 a_hi, a_lo;
#pragma unroll
        for (int j = 0; j < 8; j++) {
            __bf16 h = (__bf16)xv[j];
            a_hi[j] = h;
            a_lo[j] = (__bf16)(xv[j] - (float)h);
        }
#pragma unroll
        for (int c = 0; c < NC; c++) {
            size_t fo = (size_t)((c * 4 + s) * 64 + lane) * 8;
            bf16x8 bh = *(const bf16x8*)(Whi + fo);
            bf16x8 bl = *(const bf16x8*)(Wlo + fo);
            acc[c] = __builtin_amdgcn_mfma_f32_16x16x32_bf16(a_hi, bh, acc[c], 0, 0, 0);
            acc[c] = __builtin_amdgcn_mfma_f32_16x16x32_bf16(a_lo, bh, acc[c], 0, 0, 0);
            acc[c] = __builtin_amdgcn_mfma_f32_16x16x32_bf16(a_hi, bl, acc[c], 0, 0, 0);
        }
    }

    // C/D layout: col = c*16 + lr, row(within 16) = q*4 + r
#pragma unroll
    for (int r = 0; r < 4; r++) {
        int grow = rb + q * 4 + r;
        if (grow < N_NODES) {
            float sc = dinv[grow];
#pragma unroll
            for (int c = 0; c < NC; c++) {
                hs[(size_t)grow * 128 + c * 16 + lr] = __float2half(acc[c][r] * sc);
            }
        }
    }
}

// ---------------- FUSED: agg128(+relu) -> LDS x2 rows -> 16x64 MFMA -> hs2 --------
// block = 1024 thr = 16 waves = 16 nodes (50000 = 3125*16 exact).
// R14 gather: s_all = one coalesced idx load per 64 edges (+__shfl bcast),
// v/w double-buffer so consecutive 16-edge gather batches overlap. Row read
// as 32 lanes x float2 (full 256B line) — same as R12, register-lean.
__global__ __launch_bounds__(1024) void fused_agg_gemm_kernel(
        const __half* __restrict__ hs1, const int* __restrict__ row_off,
        const int* __restrict__ deg, const int* __restrict__ ssrc,
        const float* __restrict__ dinv, const float* __restrict__ bias,
        const __bf16* __restrict__ w2hi, const __bf16* __restrict__ w2lo,
        __half* __restrict__ hs2) {
    __shared__ float x2buf[16][132];              // pad 132: 2-way banks (free)
    int wave = threadIdx.x >> 6;
    int lane = threadIdx.x & 63;
    int rb = blockIdx.x * 16;
    int node = rb + wave;                         // always < N_NODES

    int beg = row_off[node];
    int d   = deg[node];
    float di = dinv[node];
    int hf = lane >> 5, sl = lane & 31;
    const float2* Hq = (const float2*)hs1;        // [N+1][32] 8B chunks
    float4 acc = make_float4(0.f, 0.f, 0.f, 0.f);

    for (int jj = 0; jj < d; jj += 64) {          // one idx load per 64 edges
        int s_all = ssrc[beg + jj + lane];        // coalesced, pad-32 layout safe
        int jend = d - jj; if (jend > 64) jend = 64;
        float2 v[8];
#pragma unroll
        for (int u = 0; u < 8; u++) {
            int s = __shfl(s_all, 2 * u + hf, 64);
            v[u] = Hq[(size_t)s * 32 + sl];
        }
        for (int j = 16; j < jend; j += 16) {     // padded span, sentinel-safe
            float2 w[8];
#pragma unroll
            for (int u = 0; u < 8; u++) {
                int s = __shfl(s_all, j + 2 * u + hf, 64);
                w[u] = Hq[(size_t)s * 32 + sl];   // issue before consuming v
            }
#pragma unroll
            for (int u = 0; u < 8; u++) {
                float2 f0 = __half22float2(((const __half2*)&v[u])[0]);
                float2 f1 = __half22float2(((const __half2*)&v[u])[1]);
                acc.x += f0.x; acc.y += f0.y; acc.z += f1.x; acc.w += f1.y;
            }
#pragma unroll
            for (int u = 0; u < 8; u++) v[u] = w[u];
        }
#pragma unroll
        for (int u = 0; u < 8; u++) {
            float2 f0 = __half22float2(((const __half2*)&v[u])[0]);
            float2 f1 = __half22float2(((const __half2*)&v[u])[1]);
            acc.x += f0.x; acc.y += f0.y; acc.z += f1.x; acc.w += f1.y;
        }
    }
    acc.x += __shfl_xor(acc.x, 32, 64);
    acc.y += __shfl_xor(acc.y, 32, 64);
    acc.z += __shfl_xor(acc.z, 32, 64);
    acc.w += __shfl_xor(acc.w, 32, 64);
    if (hf == 0) {
        float2 sv = Hq[(size_t)node * 32 + sl];   // self-loop
        float2 f0 = __half22float2(((const __half2*)&sv)[0]);
        float2 f1 = __half22float2(((const __half2*)&sv)[1]);
        float4 b = ((const float4*)bias)[sl];
        float4 o;
        o.x = fmaxf(fmaf(di, acc.x + f0.x, b.x), 0.f);     // relu
        o.y = fmaxf(fmaf(di, acc.y + f0.y, b.y), 0.f);
        o.z = fmaxf(fmaf(di, acc.z + f1.x, b.z), 0.f);
        o.w = fmaxf(fmaf(di, acc.w + f1.y, b.w), 0.f);
        *(float4*)&x2buf[wave][4 * sl] = o;
    }
    __syncthreads();

    // GEMM phase: waves 0-3, wave = col-frag c (16 cols each)
    if (threadIdx.x < 256) {
        int c = wave;
        int q = lane >> 4, lr = lane & 15;
        f32x4 g = (f32x4){0.f, 0.f, 0.f, 0.f};
#pragma unroll
        for (int s = 0; s < 4; s++) {
            const float* xp = &x2buf[lr][s * 32 + q * 8];
            float4 a0 = *(const float4*)xp;
            float4 a1 = *(const float4*)(xp + 4);
            float xv[8] = {a0.x, a0.y, a0.z, a0.w, a1.x, a1.y, a1.z, a1.w};
            bf16x8 a_hi, a_lo;
#pragma unroll
            for (int j = 0; j < 8; j++) {
                __bf16 h = (__bf16)xv[j];
                a_hi[j] = h;
                a_lo[j] = (__bf16)(xv[j] - (float)h);
            }
            size_t fo = (size_t)((c * 4 + s) * 64 + lane) * 8;
            bf16x8 bh = *(const bf16x8*)(w2hi + fo);
            bf16x8 bl = *(const bf16x8*)(w2lo + fo);
            g = __builtin_amdgcn_mfma_f32_16x16x32_bf16(a_hi, bh, g, 0, 0, 0);
            g = __builtin_amdgcn_mfma_f32_16x16x32_bf16(a_lo, bh, g, 0, 0, 0);
            g = __builtin_amdgcn_mfma_f32_16x16x32_bf16(a_hi, bl, g, 0, 0, 0);
        }
#pragma unroll
        for (int r = 0; r < 4; r++) {
            int grow = rb + q * 4 + r;
            hs2[(size_t)grow * 64 + c * 16 + lr] = __float2half(g[r] * dinv[grow]);
        }
    }
}

// ---------------- Aggregate CH=64: wave/node, 8B/lane = 4 rows/instr --------------
// R14: s_all coalesced idx load per 64 edges + __shfl bcast; v/w double-buffer.
__global__ __launch_bounds__(256) void aggregate64_kernel(
        const __half* __restrict__ hs, const int* __restrict__ row_off,
        const int* __restrict__ deg, const int* __restrict__ ssrc,
        const float* __restrict__ dinv, const float* __restrict__ bias,
        float* __restrict__ out) {
    int node = (blockIdx.x * 256 + threadIdx.x) >> 6;
    int lane = threadIdx.x & 63;
    if (node >= N_NODES) return;
    int beg = row_off[node];
    int d   = deg[node];
    float di = dinv[node];
    int qt = lane >> 4, sl = lane & 15;
    const float2* Hq = (const float2*)hs;        // [N+1][16] 8B chunks
    float4 acc = make_float4(0.f, 0.f, 0.f, 0.f);

    for (int jj = 0; jj < d; jj += 64) {         // one idx load per 64 edges
        int s_all = ssrc[beg + jj + lane];       // coalesced, pad-32 layout safe
        int jend = d - jj; if (jend > 64) jend = 64;
        float2 v[8];
#pragma unroll
        for (int u = 0; u < 8; u++) {
            int s = __shfl(s_all, 4 * u + qt, 64);
            v[u] = Hq[(size_t)s * 16 + sl];
        }
        for (int j = 32; j < jend; j += 32) {    // padded span, sentinel-safe
            float2 w[8];
#pragma unroll
            for (int u = 0; u < 8; u++) {
                int s = __shfl(s_all, j + 4 * u + qt, 64);
                w[u] = Hq[(size_t)s * 16 + sl];  // issue before consuming v
            }
#pragma unroll
            for (int u = 0; u < 8; u++) {
                float2 f0 = __half22float2(((const __half2*)&v[u])[0]);
                float2 f1 = __half22float2(((const __half2*)&v[u])[1]);
                acc.x += f0.x; acc.y += f0.y; acc.z += f1.x; acc.w += f1.y;
            }
#pragma unroll
            for (int u = 0; u < 8; u++) v[u] = w[u];
        }
#pragma unroll
        for (int u = 0; u < 8; u++) {
            float2 f0 = __half22float2(((const __half2*)&v[u])[0]);
            float2 f1 = __half22float2(((const __half2*)&v[u])[1]);
            acc.x += f0.x; acc.y += f0.y; acc.z += f1.x; acc.w += f1.y;
        }
    }
    acc.x += __shfl_xor(acc.x, 16, 64);
    acc.y += __shfl_xor(acc.y, 16, 64);
    acc.z += __shfl_xor(acc.z, 16, 64);
    acc.w += __shfl_xor(acc.w, 16, 64);
    acc.x += __shfl_xor(acc.x, 32, 64);
    acc.y += __shfl_xor(acc.y, 32, 64);
    acc.z += __shfl_xor(acc.z, 32, 64);
    acc.w += __shfl_xor(acc.w, 32, 64);
    if (lane < 16) {
        float2 sv = Hq[(size_t)node * 16 + sl];  // self-loop
        float2 f0 = __half22float2(((const __half2*)&sv)[0]);
        float2 f1 = __half22float2(((const __half2*)&sv)[1]);
        float4 b = ((const float4*)bias)[sl];
        float4 o;
        o.x = fmaf(di, acc.x + f0.x, b.x);
        o.y = fmaf(di, acc.y + f0.y, b.y);
        o.z = fmaf(di, acc.z + f1.x, b.z);
        o.w = fmaf(di, acc.w + f1.y, b.w);
        ((float4*)out)[(size_t)node * 16 + sl] = o;
    }
}

// ---------------- launch ----------------

extern "C" void kernel_launch(void* const* d_in, const int* in_sizes, int n_in,
                              void* d_out, int out_size, void* d_ws, size_t ws_size,
                              hipStream_t stream) {
    const float* x  = (const float*)d_in[0];   // [N,128]
    const int*   ei = (const int*)d_in[1];     // [2,E]
    const float* W1 = (const float*)d_in[2];   // [128,128]
    const float* b1 = (const float*)d_in[3];   // [128]
    const float* W2 = (const float*)d_in[4];   // [128,64]
    const float* b2 = (const float*)d_in[5];   // [64]
    float* out = (float*)d_out;                // [N,64]

    const int* src = ei;
    const int* dst = ei + N_EDGES;

    char* p = (char*)d_ws;
    size_t off = 0;
    auto alloc = [&](size_t bytes) { void* q = p + off; off += (bytes + 255) & ~(size_t)255; return q; };
    float*    dinv    = (float*)   alloc(N_NODES * 4);
    int*      deg     = (int*)     alloc(N_NODES * 4);
    int*      row_off = (int*)     alloc(N_NODES * 4);
    int*      gcur    = (int*)     alloc(NBIN * 4);
    int*      ssrc    = (int*)     alloc((size_t)NBIN * CAP2 * 4);  // 10.4 MB
    unsigned* ebin    = (unsigned*)alloc((size_t)NBIN * CAP * 4);   // 4.0 MB
    __bf16*   w1hi    = (__bf16*)  alloc(128 * 128 * 2);
    __bf16*   w1lo    = (__bf16*)  alloc(128 * 128 * 2);
    __bf16*   w2hi    = (__bf16*)  alloc(128 * 64 * 2);
    __bf16*   w2lo    = (__bf16*)  alloc(128 * 64 * 2);
    __half*   hs1     = (__half*)  alloc((size_t)(N_NODES + 1) * 128 * 2);
    __half*   hs2     = (__half*)  alloc((size_t)(N_NODES + 1) * 64 * 2);

    // 6 launches total
    prep_kernel<<<13, 256, 0, stream>>>(W1, W2, w1hi, w1lo, w2hi, w2lo, gcur, hs1, hs2);
    bin_scatter_kernel<<<NB_SCAT, 256, 0, stream>>>(src, dst, gcur, ebin);
    bin_build_kernel<<<NBIN, 256, 0, stream>>>(ebin, gcur, deg, row_off, dinv, ssrc);

    gemm_mfma128_kernel<<<(N_NODES + 63) / 64, 256, 0, stream>>>(x, w1hi, w1lo, dinv, hs1);
    fused_agg_gemm_kernel<<<N_NODES / 16, 1024, 0, stream>>>(
        hs1, row_off, deg, ssrc, dinv, b1, w2hi, w2lo, hs2);
    aggregate64_kernel<<<(N_NODES * 64 + 255) / 256, 256, 0, stream>>>(
        hs2, row_off, deg, ssrc, dinv, b2, out);
}

// Round 3
// 192.443 us; speedup vs baseline: 1.2975x; 1.0155x over previous
//
#include <hip/hip_runtime.h>
#include <hip/hip_fp16.h>

// GCN 2-layer: N=50000 nodes, E=800000 edges, 128 -> 128(relu) -> 64
// R15: R14 post-mortem: __shfl idx broadcast = ds_bpermute+lgkmcnt ahead of
//      every gather -> serialized issue, 44->52us. R13/R14 both perturbed the
//      gather BATCH structure and lost; R12's batch (8 indep scalar idx loads
//      -> 8 indep gathers) is the proven issue pattern. Kernel remains
//      latency-bound (all pipes <35%, traffic compulsory, not L2/L3-BW-bound).
//      R15 doubles per-wave MLP without touching the batch: each wave owns
//      TWO independent nodes (rb+w, rb+16+w), iterations interleaved -> two
//      8-deep gather chains in flight (16 outstanding). No launch-bounds cap
//      (1024-thr block allows up to 256 VGPR at 2 blocks/CU -> no spill).
//      Fused block = 32 nodes, GEMM widens to 8 waves x two 16x64 tiles.
//      aggregate64: same 2-nodes-per-wave interleave.
// Evidence log: R2 MLP depth win; R4/R9 sliced layouts dead; flat gather
// 86.6MB compulsory (measured 80.9MB); R11 sentinel pad win; R12 fusion
// killed 51MB x2 trip; R13 spill catastrophe (min-waves cap + fat buffers);
// R14 shfl-idx serialization; harness poison fills ~50us fixed.

#define N_NODES 50000
#define N_EDGES 800000
#define BINW    128
#define NBIN    391                    // ceil(50000/128)
#define CAP     2560                   // mean bin load 2046, ~11 sigma margin
#define CAP2    6656                   // padded: up to 2560 + 128*31
#define B_CHUNK 2048
#define NB_SCAT ((N_EDGES + B_CHUNK - 1) / B_CHUNK)   // 391

typedef __bf16 bf16x8 __attribute__((ext_vector_type(8)));
typedef float  f32x4  __attribute__((ext_vector_type(4)));

// ---------------- prep: W-frags, zero gcur, zero sentinel rows ----------------
template<int N>
__device__ inline void wprep_body(const float* __restrict__ W,
                                  __bf16* __restrict__ hi, __bf16* __restrict__ lo,
                                  int idx) {
    if (idx >= (N / 16) * 4 * 64) return;
    int l = idx & 63;
    int s = (idx >> 6) & 3;
    int c = idx >> 8;
    int n = c * 16 + (l & 15);
    int k0 = s * 32 + (l >> 4) * 8;
#pragma unroll
    for (int j = 0; j < 8; j++) {
        float w = W[(k0 + j) * N + n];
        __bf16 h = (__bf16)w;
        hi[idx * 8 + j] = h;
        lo[idx * 8 + j] = (__bf16)(w - (float)h);
    }
}

__global__ __launch_bounds__(256) void prep_kernel(
        const float* __restrict__ W1, const float* __restrict__ W2,
        __bf16* __restrict__ w1hi, __bf16* __restrict__ w1lo,
        __bf16* __restrict__ w2hi, __bf16* __restrict__ w2lo,
        int* __restrict__ gcur, __half* __restrict__ hs1, __half* __restrict__ hs2) {
    int b = blockIdx.x, tid = threadIdx.x;
    if (b < 8)       wprep_body<128>(W1, w1hi, w1lo, b * 256 + tid);
    else if (b < 12) wprep_body<64> (W2, w2hi, w2lo, (b - 8) * 256 + tid);
    else {
        for (int i = tid; i < NBIN; i += 256) gcur[i] = 0;
        if (tid < 128) hs1[(size_t)N_NODES * 128 + tid] = __float2half(0.f);
        if (tid < 64)  hs2[(size_t)N_NODES * 64 + tid] = __float2half(0.f);
    }
}

// ---------------- bin_scatter: one edge pass -> per-bin packed (dst<<16|src) -------

__global__ __launch_bounds__(256) void bin_scatter_kernel(
        const int* __restrict__ src, const int* __restrict__ dst,
        int* __restrict__ gcur, unsigned* __restrict__ ebin) {
    __shared__ int cnt[512];
    __shared__ int boff[512];
    __shared__ int bcur[512];
    __shared__ int gbase[512];
    __shared__ unsigned stage[B_CHUNK];
    __shared__ int ex[256];
    int tid = threadIdx.x;
    int e0 = blockIdx.x * B_CHUNK;

    cnt[tid] = 0; cnt[tid + 256] = 0;
    __syncthreads();

    unsigned key[8]; int bins[8];
#pragma unroll
    for (int i = 0; i < 8; i++) {
        int e = e0 + tid + i * 256;               // coalesced
        if (e < N_EDGES) {
            int d = dst[e], s = src[e];
            key[i]  = ((unsigned)d << 16) | (unsigned)s;
            bins[i] = d >> 7;
            atomicAdd(&cnt[bins[i]], 1);
        } else bins[i] = -1;
    }
    __syncthreads();

    // exclusive scan of 512 bin counts with 256 threads (2 bins each)
    int a = cnt[2 * tid], b = cnt[2 * tid + 1];
    ex[tid] = a + b;
    __syncthreads();
    for (int off = 1; off < 256; off <<= 1) {
        int t = (tid >= off) ? ex[tid - off] : 0;
        __syncthreads();
        ex[tid] += t;
        __syncthreads();
    }
    int myex = ex[tid] - (a + b);
    boff[2 * tid] = myex;     boff[2 * tid + 1] = myex + a;
    bcur[2 * tid] = myex;     bcur[2 * tid + 1] = myex + a;
    __syncthreads();

    // compact into bin-contiguous staging
#pragma unroll
    for (int i = 0; i < 8; i++) {
        if (bins[i] >= 0) {
            int p = atomicAdd(&bcur[bins[i]], 1);
            stage[p] = key[i];
        }
    }

    // bulk-reserve global bin space (one atomic per non-empty (block,bin))
    __syncthreads();
    for (int b2 = tid; b2 < NBIN; b2 += 256) {
        int c = cnt[b2];
        gbase[b2] = (c > 0) ? atomicAdd(&gcur[b2], c) : 0;
    }
    __syncthreads();

    int total = N_EDGES - e0; if (total > B_CHUNK) total = B_CHUNK;
    for (int i = tid; i < total; i += 256) {
        unsigned k = stage[i];
        int bin = (int)(k >> 23);                 // dst>>7
        int idx = gbase[bin] + (i - boff[bin]);
        if (idx < CAP) ebin[(size_t)bin * CAP + idx] = k;  // guard (11-sigma)
    }
}

// ---------------- bin_build: histogram + padded scan + sentinel fill ---------------
__global__ __launch_bounds__(256) void bin_build_kernel(
        const unsigned* __restrict__ ebin, const int* __restrict__ gcur,
        int* __restrict__ deg, int* __restrict__ row_off,
        float* __restrict__ dinv, int* __restrict__ ssrc) {
    __shared__ int dl[BINW];
    __shared__ int pref[BINW];
    __shared__ int cur[BINW];
    __shared__ int padTotal;
    int bin = blockIdx.x, tid = threadIdx.x;
    if (tid < BINW) dl[tid] = 0;
    __syncthreads();
    int cnt = gcur[bin]; if (cnt > CAP) cnt = CAP;
    const unsigned* eb = ebin + (size_t)bin * CAP;
    for (int i = tid; i < cnt; i += 256)
        atomicAdd(&dl[(eb[i] >> 16) & 127], 1);
    __syncthreads();
    // Hillis-Steele inclusive scan over 128 PADDED counts
    int pc = 0;
    if (tid < BINW) { pc = (dl[tid] + 31) & ~31; pref[tid] = pc; }
    __syncthreads();
    for (int off = 1; off < BINW; off <<= 1) {
        int t = 0;
        if (tid < BINW && tid >= off) t = pref[tid - off];
        __syncthreads();
        if (tid < BINW) pref[tid] += t;
        __syncthreads();
    }
    if (tid < BINW) {
        int ex = pref[tid] - pc;                  // padded exclusive prefix
        cur[tid] = ex;
        int node = bin * BINW + tid;
        if (node < N_NODES) {
            deg[node]     = dl[tid];
            row_off[node] = bin * CAP2 + ex;
            dinv[node]    = rsqrtf((float)(dl[tid] + 1));   // +1 self-loop
        }
        if (tid == BINW - 1) padTotal = pref[tid];
    }
    __syncthreads();
    int pt = padTotal;
    int* sb = ssrc + (size_t)bin * CAP2;
    for (int i = tid; i < pt; i += 256) sb[i] = N_NODES;    // sentinel prefill
    __syncthreads();
    for (int i = tid; i < cnt; i += 256) {
        unsigned k = eb[i];
        int p = atomicAdd(&cur[(k >> 16) & 127], 1);
        sb[p] = (int)(k & 0xFFFFu);
    }
}

// ---------------- GEMM layer1: hs1[row][128] = fp16( dinv[row]*(X@W1)[row] ) ------
__global__ __launch_bounds__(256) void gemm_mfma128_kernel(
        const float* __restrict__ X, const __bf16* __restrict__ Whi,
        const __bf16* __restrict__ Wlo, const float* __restrict__ dinv,
        __half* __restrict__ hs) {
    constexpr int NC = 8;
    int tid = threadIdx.x;
    int w = tid >> 6, lane = tid & 63;
    int q = lane >> 4, lr = lane & 15;
    int rb = blockIdx.x * 64 + w * 16;
    int row = rb + lr;
    int rowc = (row < N_NODES) ? row : (N_NODES - 1);

    f32x4 acc[NC];
#pragma unroll
    for (int c = 0; c < NC; c++) acc[c] = (f32x4){0.f, 0.f, 0.f, 0.f};

#pragma unroll
    for (int s = 0; s < 4; s++) {
        const float* xp = X + (size_t)rowc * 128 + s * 32 + q * 8;
        float4 x0 = *(const float4*)xp;
        float4 x1 = *(const float4*)(xp + 4);
        float xv[8] = {x0.x, x0.y, x0.z, x0.w, x1.x, x1.y, x1.z, x1.w};
        bf16x8 a_hi, a_lo;
#pragma unroll
        for (int j = 0; j < 8; j++) {
            __bf16 h = (__bf16)xv[j];
            a_hi[j] = h;
            a_lo[j] = (__bf16)(xv[j] - (float)h);
        }
#pragma unroll
        for (int c = 0; c < NC; c++) {
            size_t fo = (size_t)((c * 4 + s) * 64 + lane) * 8;
            bf16x8 bh = *(const bf16x8*)(Whi + fo);
            bf16x8 bl = *(const bf16x8*)(Wlo + fo);
            acc[c] = __builtin_amdgcn_mfma_f32_16x16x32_bf16(a_hi, bh, acc[c], 0, 0, 0);
            acc[c] = __builtin_amdgcn_mfma_f32_16x16x32_bf16(a_lo, bh, acc[c], 0, 0, 0);
            acc[c] = __builtin_amdgcn_mfma_f32_16x16x32_bf16(a_hi, bl, acc[c], 0, 0, 0);
        }
    }

    // C/D layout: col = c*16 + lr, row(within 16) = q*4 + r
#pragma unroll
    for (int r = 0; r < 4; r++) {
        int grow = rb + q * 4 + r;
        if (grow < N_NODES) {
            float sc = dinv[grow];
#pragma unroll
            for (int c = 0; c < NC; c++) {
                hs[(size_t)grow * 128 + c * 16 + lr] = __float2half(acc[c][r] * sc);
            }
        }
    }
}

// ---------------- FUSED: agg128(+relu) x2 nodes/wave -> LDS -> 2x 16x64 MFMA ------
// block = 1024 thr = 16 waves = 32 nodes. Wave w gathers nodes rb+w and
// rb+16+w with interleaved iterations: two independent 8-deep gather chains
// in flight (R12 batch structure per node, untouched). GEMM phase: 8 waves,
// wave = (tile t = w>>2, col-frag c = w&3).
__global__ __launch_bounds__(1024) void fused_agg_gemm_kernel(
        const __half* __restrict__ hs1, const int* __restrict__ row_off,
        const int* __restrict__ deg, const int* __restrict__ ssrc,
        const float* __restrict__ dinv, const float* __restrict__ bias,
        const __bf16* __restrict__ w2hi, const __bf16* __restrict__ w2lo,
        __half* __restrict__ hs2) {
    __shared__ float x2buf[32][132];              // pad 132: 2-way banks (free)
    int wave = threadIdx.x >> 6;
    int lane = threadIdx.x & 63;
    int rb = blockIdx.x * 32;
    int n0 = rb + wave;                           // always < N (rb<=49984)
    int n1 = rb + 16 + wave;                      // may be >= N in last block
    bool has1 = (n1 < N_NODES);
    int n1c = has1 ? n1 : n0;

    int beg0 = row_off[n0];
    int d0   = deg[n0];
    float di0 = dinv[n0];
    int beg1 = row_off[n1c];
    int d1   = has1 ? deg[n1c] : 0;
    float di1 = dinv[n1c];

    int hf = lane >> 5, sl = lane & 31;
    const float2* Hq = (const float2*)hs1;        // [N+1][32] 8B chunks
    float4 acc0 = make_float4(0.f, 0.f, 0.f, 0.f);
    float4 acc1 = make_float4(0.f, 0.f, 0.f, 0.f);

    int dm = d0 > d1 ? d0 : d1;
    for (int j = 0; j < dm; j += 16) {            // padded spans, sentinel-safe
        bool a = j < d0, b = j < d1;              // wave-uniform predicates
        int sA[8], sB[8];
        float2 vA[8], vB[8];
        if (a) {
#pragma unroll
            for (int u = 0; u < 8; u++) sA[u] = ssrc[beg0 + j + 2 * u + hf];
#pragma unroll
            for (int u = 0; u < 8; u++) vA[u] = Hq[(size_t)sA[u] * 32 + sl];
        }
        if (b) {
#pragma unroll
            for (int u = 0; u < 8; u++) sB[u] = ssrc[beg1 + j + 2 * u + hf];
#pragma unroll
            for (int u = 0; u < 8; u++) vB[u] = Hq[(size_t)sB[u] * 32 + sl];
        }
        if (a) {
#pragma unroll
            for (int u = 0; u < 8; u++) {
                float2 f0 = __half22float2(((const __half2*)&vA[u])[0]);
                float2 f1 = __half22float2(((const __half2*)&vA[u])[1]);
                acc0.x += f0.x; acc0.y += f0.y; acc0.z += f1.x; acc0.w += f1.y;
            }
        }
        if (b) {
#pragma unroll
            for (int u = 0; u < 8; u++) {
                float2 f0 = __half22float2(((const __half2*)&vB[u])[0]);
                float2 f1 = __half22float2(((const __half2*)&vB[u])[1]);
                acc1.x += f0.x; acc1.y += f0.y; acc1.z += f1.x; acc1.w += f1.y;
            }
        }
    }
    acc0.x += __shfl_xor(acc0.x, 32, 64);
    acc0.y += __shfl_xor(acc0.y, 32, 64);
    acc0.z += __shfl_xor(acc0.z, 32, 64);
    acc0.w += __shfl_xor(acc0.w, 32, 64);
    acc1.x += __shfl_xor(acc1.x, 32, 64);
    acc1.y += __shfl_xor(acc1.y, 32, 64);
    acc1.z += __shfl_xor(acc1.z, 32, 64);
    acc1.w += __shfl_xor(acc1.w, 32, 64);
    if (hf == 0) {
        float4 bia = ((const float4*)bias)[sl];
        {   // node 0 epilogue
            float2 sv = Hq[(size_t)n0 * 32 + sl];           // self-loop
            float2 f0 = __half22float2(((const __half2*)&sv)[0]);
            float2 f1 = __half22float2(((const __half2*)&sv)[1]);
            float4 o;
            o.x = fmaxf(fmaf(di0, acc0.x + f0.x, bia.x), 0.f);   // relu
            o.y = fmaxf(fmaf(di0, acc0.y + f0.y, bia.y), 0.f);
            o.z = fmaxf(fmaf(di0, acc0.z + f1.x, bia.z), 0.f);
            o.w = fmaxf(fmaf(di0, acc0.w + f1.y, bia.w), 0.f);
            *(float4*)&x2buf[wave][4 * sl] = o;
        }
        if (has1) {  // node 1 epilogue
            float2 sv = Hq[(size_t)n1 * 32 + sl];
            float2 f0 = __half22float2(((const __half2*)&sv)[0]);
            float2 f1 = __half22float2(((const __half2*)&sv)[1]);
            float4 o;
            o.x = fmaxf(fmaf(di1, acc1.x + f0.x, bia.x), 0.f);
            o.y = fmaxf(fmaf(di1, acc1.y + f0.y, bia.y), 0.f);
            o.z = fmaxf(fmaf(di1, acc1.z + f1.x, bia.z), 0.f);
            o.w = fmaxf(fmaf(di1, acc1.w + f1.y, bia.w), 0.f);
            *(float4*)&x2buf[wave + 16][4 * sl] = o;
        } else {
            *(float4*)&x2buf[wave + 16][4 * sl] = make_float4(0.f, 0.f, 0.f, 0.f);
        }
    }
    __syncthreads();

    // GEMM phase: waves 0-7; tile t = wave>>2 (rows t*16..), col-frag c = wave&3
    if (threadIdx.x < 512) {
        int t = wave >> 2, c = wave & 3;
        int q = lane >> 4, lr = lane & 15;
        f32x4 g = (f32x4){0.f, 0.f, 0.f, 0.f};
#pragma unroll
        for (int s = 0; s < 4; s++) {
            const float* xp = &x2buf[t * 16 + lr][s * 32 + q * 8];
            float4 a0 = *(const float4*)xp;
            float4 a1 = *(const float4*)(xp + 4);
            float xv[8] = {a0.x, a0.y, a0.z, a0.w, a1.x, a1.y, a1.z, a1.w};
            bf16x8 a_hi, a_lo;
#pragma unroll
            for (int j = 0; j < 8; j++) {
                __bf16 h = (__bf16)xv[j];
                a_hi[j] = h;
                a_lo[j] = (__bf16)(xv[j] - (float)h);
            }
            size_t fo = (size_t)((c * 4 + s) * 64 + lane) * 8;
            bf16x8 bh = *(const bf16x8*)(w2hi + fo);
            bf16x8 bl = *(const bf16x8*)(w2lo + fo);
            g = __builtin_amdgcn_mfma_f32_16x16x32_bf16(a_hi, bh, g, 0, 0, 0);
            g = __builtin_amdgcn_mfma_f32_16x16x32_bf16(a_lo, bh, g, 0, 0, 0);
            g = __builtin_amdgcn_mfma_f32_16x16x32_bf16(a_hi, bl, g, 0, 0, 0);
        }
#pragma unroll
        for (int r = 0; r < 4; r++) {
            int grow = rb + t * 16 + q * 4 + r;
            if (grow < N_NODES) {
                hs2[(size_t)grow * 64 + c * 16 + lr] = __float2half(g[r] * dinv[grow]);
            }
        }
    }
}

// ---------------- Aggregate CH=64: wave handles 2 nodes, interleaved --------------
// R15: two independent 8-deep gather chains per wave (R12 batch per node).
__global__ __launch_bounds__(256) void aggregate64_kernel(
        const __half* __restrict__ hs, const int* __restrict__ row_off,
        const int* __restrict__ deg, const int* __restrict__ ssrc,
        const float* __restrict__ dinv, const float* __restrict__ bias,
        float* __restrict__ out) {
    int gw = (blockIdx.x * 256 + threadIdx.x) >> 6;
    int lane = threadIdx.x & 63;
    int n0 = gw * 2, n1 = gw * 2 + 1;             // N even -> n1 valid iff n0 is
    if (n0 >= N_NODES) return;
    int beg0 = row_off[n0], d0 = deg[n0];
    int beg1 = row_off[n1], d1 = deg[n1];
    float di0 = dinv[n0], di1 = dinv[n1];
    int qt = lane >> 4, sl = lane & 15;
    const float2* Hq = (const float2*)hs;         // [N+1][16] 8B chunks
    float4 acc0 = make_float4(0.f, 0.f, 0.f, 0.f);
    float4 acc1 = make_float4(0.f, 0.f, 0.f, 0.f);

    int dm = d0 > d1 ? d0 : d1;
    for (int j = 0; j < dm; j += 32) {            // padded spans, sentinel-safe
        bool a = j < d0, b = j < d1;              // wave-uniform
        int sA[8], sB[8];
        float2 vA[8], vB[8];
        if (a) {
#pragma unroll
            for (int u = 0; u < 8; u++) sA[u] = ssrc[beg0 + j + 4 * u + qt];
#pragma unroll
            for (int u = 0; u < 8; u++) vA[u] = Hq[(size_t)sA[u] * 16 + sl];
        }
        if (b) {
#pragma unroll
            for (int u = 0; u < 8; u++) sB[u] = ssrc[beg1 + j + 4 * u + qt];
#pragma unroll
            for (int u = 0; u < 8; u++) vB[u] = Hq[(size_t)sB[u] * 16 + sl];
        }
        if (a) {
#pragma unroll
            for (int u = 0; u < 8; u++) {
                float2 f0 = __half22float2(((const __half2*)&vA[u])[0]);
                float2 f1 = __half22float2(((const __half2*)&vA[u])[1]);
                acc0.x += f0.x; acc0.y += f0.y; acc0.z += f1.x; acc0.w += f1.y;
            }
        }
        if (b) {
#pragma unroll
            for (int u = 0; u < 8; u++) {
                float2 f0 = __half22float2(((const __half2*)&vB[u])[0]);
                float2 f1 = __half22float2(((const __half2*)&vB[u])[1]);
                acc1.x += f0.x; acc1.y += f0.y; acc1.z += f1.x; acc1.w += f1.y;
            }
        }
    }
#pragma unroll
    for (int o = 16; o <= 32; o <<= 1) {
        acc0.x += __shfl_xor(acc0.x, o, 64);
        acc0.y += __shfl_xor(acc0.y, o, 64);
        acc0.z += __shfl_xor(acc0.z, o, 64);
        acc0.w += __shfl_xor(acc0.w, o, 64);
        acc1.x += __shfl_xor(acc1.x, o, 64);
        acc1.y += __shfl_xor(acc1.y, o, 64);
        acc1.z += __shfl_xor(acc1.z, o, 64);
        acc1.w += __shfl_xor(acc1.w, o, 64);
    }
    if (lane < 16) {
        float4 b = ((const float4*)bias)[sl];
        {   // node 0
            float2 sv = Hq[(size_t)n0 * 16 + sl];  // self-loop
            float2 f0 = __half22float2(((const __half2*)&sv)[0]);
            float2 f1 = __half22float2(((const __half2*)&sv)[1]);
            float4 o;
            o.x = fmaf(di0, acc0.x + f0.x, b.x);
            o.y = fmaf(di0, acc0.y + f0.y, b.y);
            o.z = fmaf(di0, acc0.z + f1.x, b.z);
            o.w = fmaf(di0, acc0.w + f1.y, b.w);
            ((float4*)out)[(size_t)n0 * 16 + sl] = o;
        }
        {   // node 1
            float2 sv = Hq[(size_t)n1 * 16 + sl];
            float2 f0 = __half22float2(((const __half2*)&sv)[0]);
            float2 f1 = __half22float2(((const __half2*)&sv)[1]);
            float4 o;
            o.x = fmaf(di1, acc1.x + f0.x, b.x);
            o.y = fmaf(di1, acc1.y + f0.y, b.y);
            o.z = fmaf(di1, acc1.z + f1.x, b.z);
            o.w = fmaf(di1, acc1.w + f1.y, b.w);
            ((float4*)out)[(size_t)n1 * 16 + sl] = o;
        }
    }
}

// ---------------- launch ----------------

extern "C" void kernel_launch(void* const* d_in, const int* in_sizes, int n_in,
                              void* d_out, int out_size, void* d_ws, size_t ws_size,
                              hipStream_t stream) {
    const float* x  = (const float*)d_in[0];   // [N,128]
    const int*   ei = (const int*)d_in[1];     // [2,E]
    const float* W1 = (const float*)d_in[2];   // [128,128]
    const float* b1 = (const float*)d_in[3];   // [128]
    const float* W2 = (const float*)d_in[4];   // [128,64]
    const float* b2 = (const float*)d_in[5];   // [64]
    float* out = (float*)d_out;                // [N,64]

    const int* src = ei;
    const int* dst = ei + N_EDGES;

    char* p = (char*)d_ws;
    size_t off = 0;
    auto alloc = [&](size_t bytes) { void* q = p + off; off += (bytes + 255) & ~(size_t)255; return q; };
    float*    dinv    = (float*)   alloc(N_NODES * 4);
    int*      deg     = (int*)     alloc(N_NODES * 4);
    int*      row_off = (int*)     alloc(N_NODES * 4);
    int*      gcur    = (int*)     alloc(NBIN * 4);
    int*      ssrc    = (int*)     alloc((size_t)NBIN * CAP2 * 4);  // 10.4 MB
    unsigned* ebin    = (unsigned*)alloc((size_t)NBIN * CAP * 4);   // 4.0 MB
    __bf16*   w1hi    = (__bf16*)  alloc(128 * 128 * 2);
    __bf16*   w1lo    = (__bf16*)  alloc(128 * 128 * 2);
    __bf16*   w2hi    = (__bf16*)  alloc(128 * 64 * 2);
    __bf16*   w2lo    = (__bf16*)  alloc(128 * 64 * 2);
    __half*   hs1     = (__half*)  alloc((size_t)(N_NODES + 1) * 128 * 2);
    __half*   hs2     = (__half*)  alloc((size_t)(N_NODES + 1) * 64 * 2);

    // 6 launches total
    prep_kernel<<<13, 256, 0, stream>>>(W1, W2, w1hi, w1lo, w2hi, w2lo, gcur, hs1, hs2);
    bin_scatter_kernel<<<NB_SCAT, 256, 0, stream>>>(src, dst, gcur, ebin);
    bin_build_kernel<<<NBIN, 256, 0, stream>>>(ebin, gcur, deg, row_off, dinv, ssrc);

    gemm_mfma128_kernel<<<(N_NODES + 63) / 64, 256, 0, stream>>>(x, w1hi, w1lo, dinv, hs1);
    fused_agg_gemm_kernel<<<(N_NODES + 31) / 32, 1024, 0, stream>>>(
        hs1, row_off, deg, ssrc, dinv, b1, w2hi, w2lo, hs2);
    aggregate64_kernel<<<((N_NODES / 2) * 64 + 255) / 256, 256, 0, stream>>>(
        hs2, row_off, deg, ssrc, dinv, b2, out);
}

// Round 4
// 174.418 us; speedup vs baseline: 1.4316x; 1.1033x over previous
//
#include <hip/hip_runtime.h>
#include <hip/hip_fp16.h>

// GCN 2-layer: N=50000 nodes, E=800000 edges, 128 -> 128(relu) -> 64
// R16: gather rebuilt around UNIFORM row indices. One coalesced idx load
//      covers 64 edges (s_all); __builtin_amdgcn_readlane (VALU->SGPR, NO
//      lgkm/vm counter — unlike R14's ds_bpermute) makes each idx
//      wave-uniform, so each gather is a whole-wave 256B row read with a
//      SCALAR base (saddr form): addressing on SALU, lane = channel pair,
//      no final shuffle reduction. Per node (deg padded to 32): ONE idx
//      roundtrip + ONE 32-deep gather burst (MLP 32/wave vs 8). vv[32]
//      buffer = 32 VGPR, total ~55 — under the 64-reg/2-block cliff, NO
//      launch-bounds cap (R13 lesson). deg>32 batch serialized (P~1e-4).
//      aggregate64: same structure, ushort loads (64x2B = 128B row).
// Evidence log: R2 MLP depth win; R4/R9 sliced layouts dead; flat gather
// 86.6MB compulsory; R11 sentinel pad win; R12 fusion killed 51MB x2 trip;
// R13 spill catastrophe (min-waves cap + fat buffers); R14 shfl-idx via
// ds_bpermute serialization; R15 branchy 2-node interleave neutral-negative;
// harness poison fills ~50us fixed.

#define N_NODES 50000
#define N_EDGES 800000
#define BINW    128
#define NBIN    391                    // ceil(50000/128)
#define CAP     2560                   // mean bin load 2046, ~11 sigma margin
#define CAP2    6656                   // padded: up to 2560 + 128*31
#define B_CHUNK 2048
#define NB_SCAT ((N_EDGES + B_CHUNK - 1) / B_CHUNK)   // 391

typedef __bf16 bf16x8 __attribute__((ext_vector_type(8)));
typedef float  f32x4  __attribute__((ext_vector_type(4)));

// ---------------- prep: W-frags, zero gcur, zero sentinel rows ----------------
template<int N>
__device__ inline void wprep_body(const float* __restrict__ W,
                                  __bf16* __restrict__ hi, __bf16* __restrict__ lo,
                                  int idx) {
    if (idx >= (N / 16) * 4 * 64) return;
    int l = idx & 63;
    int s = (idx >> 6) & 3;
    int c = idx >> 8;
    int n = c * 16 + (l & 15);
    int k0 = s * 32 + (l >> 4) * 8;
#pragma unroll
    for (int j = 0; j < 8; j++) {
        float w = W[(k0 + j) * N + n];
        __bf16 h = (__bf16)w;
        hi[idx * 8 + j] = h;
        lo[idx * 8 + j] = (__bf16)(w - (float)h);
    }
}

__global__ __launch_bounds__(256) void prep_kernel(
        const float* __restrict__ W1, const float* __restrict__ W2,
        __bf16* __restrict__ w1hi, __bf16* __restrict__ w1lo,
        __bf16* __restrict__ w2hi, __bf16* __restrict__ w2lo,
        int* __restrict__ gcur, __half* __restrict__ hs1, __half* __restrict__ hs2) {
    int b = blockIdx.x, tid = threadIdx.x;
    if (b < 8)       wprep_body<128>(W1, w1hi, w1lo, b * 256 + tid);
    else if (b < 12) wprep_body<64> (W2, w2hi, w2lo, (b - 8) * 256 + tid);
    else {
        for (int i = tid; i < NBIN; i += 256) gcur[i] = 0;
        if (tid < 128) hs1[(size_t)N_NODES * 128 + tid] = __float2half(0.f);
        if (tid < 64)  hs2[(size_t)N_NODES * 64 + tid] = __float2half(0.f);
    }
}

// ---------------- bin_scatter: one edge pass -> per-bin packed (dst<<16|src) -------

__global__ __launch_bounds__(256) void bin_scatter_kernel(
        const int* __restrict__ src, const int* __restrict__ dst,
        int* __restrict__ gcur, unsigned* __restrict__ ebin) {
    __shared__ int cnt[512];
    __shared__ int boff[512];
    __shared__ int bcur[512];
    __shared__ int gbase[512];
    __shared__ unsigned stage[B_CHUNK];
    __shared__ int ex[256];
    int tid = threadIdx.x;
    int e0 = blockIdx.x * B_CHUNK;

    cnt[tid] = 0; cnt[tid + 256] = 0;
    __syncthreads();

    unsigned key[8]; int bins[8];
#pragma unroll
    for (int i = 0; i < 8; i++) {
        int e = e0 + tid + i * 256;               // coalesced
        if (e < N_EDGES) {
            int d = dst[e], s = src[e];
            key[i]  = ((unsigned)d << 16) | (unsigned)s;
            bins[i] = d >> 7;
            atomicAdd(&cnt[bins[i]], 1);
        } else bins[i] = -1;
    }
    __syncthreads();

    // exclusive scan of 512 bin counts with 256 threads (2 bins each)
    int a = cnt[2 * tid], b = cnt[2 * tid + 1];
    ex[tid] = a + b;
    __syncthreads();
    for (int off = 1; off < 256; off <<= 1) {
        int t = (tid >= off) ? ex[tid - off] : 0;
        __syncthreads();
        ex[tid] += t;
        __syncthreads();
    }
    int myex = ex[tid] - (a + b);
    boff[2 * tid] = myex;     boff[2 * tid + 1] = myex + a;
    bcur[2 * tid] = myex;     bcur[2 * tid + 1] = myex + a;
    __syncthreads();

    // compact into bin-contiguous staging
#pragma unroll
    for (int i = 0; i < 8; i++) {
        if (bins[i] >= 0) {
            int p = atomicAdd(&bcur[bins[i]], 1);
            stage[p] = key[i];
        }
    }

    // bulk-reserve global bin space (one atomic per non-empty (block,bin))
    __syncthreads();
    for (int b2 = tid; b2 < NBIN; b2 += 256) {
        int c = cnt[b2];
        gbase[b2] = (c > 0) ? atomicAdd(&gcur[b2], c) : 0;
    }
    __syncthreads();

    int total = N_EDGES - e0; if (total > B_CHUNK) total = B_CHUNK;
    for (int i = tid; i < total; i += 256) {
        unsigned k = stage[i];
        int bin = (int)(k >> 23);                 // dst>>7
        int idx = gbase[bin] + (i - boff[bin]);
        if (idx < CAP) ebin[(size_t)bin * CAP + idx] = k;  // guard (11-sigma)
    }
}

// ---------------- bin_build: histogram + padded scan + sentinel fill ---------------
__global__ __launch_bounds__(256) void bin_build_kernel(
        const unsigned* __restrict__ ebin, const int* __restrict__ gcur,
        int* __restrict__ deg, int* __restrict__ row_off,
        float* __restrict__ dinv, int* __restrict__ ssrc) {
    __shared__ int dl[BINW];
    __shared__ int pref[BINW];
    __shared__ int cur[BINW];
    __shared__ int padTotal;
    int bin = blockIdx.x, tid = threadIdx.x;
    if (tid < BINW) dl[tid] = 0;
    __syncthreads();
    int cnt = gcur[bin]; if (cnt > CAP) cnt = CAP;
    const unsigned* eb = ebin + (size_t)bin * CAP;
    for (int i = tid; i < cnt; i += 256)
        atomicAdd(&dl[(eb[i] >> 16) & 127], 1);
    __syncthreads();
    // Hillis-Steele inclusive scan over 128 PADDED counts
    int pc = 0;
    if (tid < BINW) { pc = (dl[tid] + 31) & ~31; pref[tid] = pc; }
    __syncthreads();
    for (int off = 1; off < BINW; off <<= 1) {
        int t = 0;
        if (tid < BINW && tid >= off) t = pref[tid - off];
        __syncthreads();
        if (tid < BINW) pref[tid] += t;
        __syncthreads();
    }
    if (tid < BINW) {
        int ex = pref[tid] - pc;                  // padded exclusive prefix
        cur[tid] = ex;
        int node = bin * BINW + tid;
        if (node < N_NODES) {
            deg[node]     = dl[tid];
            row_off[node] = bin * CAP2 + ex;
            dinv[node]    = rsqrtf((float)(dl[tid] + 1));   // +1 self-loop
        }
        if (tid == BINW - 1) padTotal = pref[tid];
    }
    __syncthreads();
    int pt = padTotal;
    int* sb = ssrc + (size_t)bin * CAP2;
    for (int i = tid; i < pt; i += 256) sb[i] = N_NODES;    // sentinel prefill
    __syncthreads();
    for (int i = tid; i < cnt; i += 256) {
        unsigned k = eb[i];
        int p = atomicAdd(&cur[(k >> 16) & 127], 1);
        sb[p] = (int)(k & 0xFFFFu);
    }
}

// ---------------- GEMM layer1: hs1[row][128] = fp16( dinv[row]*(X@W1)[row] ) ------
__global__ __launch_bounds__(256) void gemm_mfma128_kernel(
        const float* __restrict__ X, const __bf16* __restrict__ Whi,
        const __bf16* __restrict__ Wlo, const float* __restrict__ dinv,
        __half* __restrict__ hs) {
    constexpr int NC = 8;
    int tid = threadIdx.x;
    int w = tid >> 6, lane = tid & 63;
    int q = lane >> 4, lr = lane & 15;
    int rb = blockIdx.x * 64 + w * 16;
    int row = rb + lr;
    int rowc = (row < N_NODES) ? row : (N_NODES - 1);

    f32x4 acc[NC];
#pragma unroll
    for (int c = 0; c < NC; c++) acc[c] = (f32x4){0.f, 0.f, 0.f, 0.f};

#pragma unroll
    for (int s = 0; s < 4; s++) {
        const float* xp = X + (size_t)rowc * 128 + s * 32 + q * 8;
        float4 x0 = *(const float4*)xp;
        float4 x1 = *(const float4*)(xp + 4);
        float xv[8] = {x0.x, x0.y, x0.z, x0.w, x1.x, x1.y, x1.z, x1.w};
        bf16x8 a_hi, a_lo;
#pragma unroll
        for (int j = 0; j < 8; j++) {
            __bf16 h = (__bf16)xv[j];
            a_hi[j] = h;
            a_lo[j] = (__bf16)(xv[j] - (float)h);
        }
#pragma unroll
        for (int c = 0; c < NC; c++) {
            size_t fo = (size_t)((c * 4 + s) * 64 + lane) * 8;
            bf16x8 bh = *(const bf16x8*)(Whi + fo);
            bf16x8 bl = *(const bf16x8*)(Wlo + fo);
            acc[c] = __builtin_amdgcn_mfma_f32_16x16x32_bf16(a_hi, bh, acc[c], 0, 0, 0);
            acc[c] = __builtin_amdgcn_mfma_f32_16x16x32_bf16(a_lo, bh, acc[c], 0, 0, 0);
            acc[c] = __builtin_amdgcn_mfma_f32_16x16x32_bf16(a_hi, bl, acc[c], 0, 0, 0);
        }
    }

    // C/D layout: col = c*16 + lr, row(within 16) = q*4 + r
#pragma unroll
    for (int r = 0; r < 4; r++) {
        int grow = rb + q * 4 + r;
        if (grow < N_NODES) {
            float sc = dinv[grow];
#pragma unroll
            for (int c = 0; c < NC; c++) {
                hs[(size_t)grow * 128 + c * 16 + lr] = __float2half(acc[c][r] * sc);
            }
        }
    }
}

// ---------------- FUSED: agg128(+relu) -> LDS x2 rows -> 16x64 MFMA -> hs2 --------
// block = 1024 thr = 16 waves = 16 nodes (50000 = 3125*16 exact).
// R16 gather: s_all (1 coalesced load / 64 edges) -> readlane -> uniform row
// index -> whole-wave 256B row read (lane = channel pair, scalar base).
// One idx roundtrip + one 32-deep gather burst per node (deg padded to 32).
__global__ __launch_bounds__(1024) void fused_agg_gemm_kernel(
        const __half* __restrict__ hs1, const int* __restrict__ row_off,
        const int* __restrict__ deg, const int* __restrict__ ssrc,
        const float* __restrict__ dinv, const float* __restrict__ bias,
        const __bf16* __restrict__ w2hi, const __bf16* __restrict__ w2lo,
        __half* __restrict__ hs2) {
    __shared__ float x2buf[16][132];              // pad 132: 2-way banks (free)
    int wave = threadIdx.x >> 6;
    int lane = threadIdx.x & 63;
    int rb = blockIdx.x * 16;
    int node = rb + wave;                         // always < N_NODES

    int beg = __builtin_amdgcn_readfirstlane(row_off[node]);
    int d   = __builtin_amdgcn_readfirstlane(deg[node]);
    float di = dinv[node];
    const char* Hb = (const char*)hs1;            // row stride 256B
    float ax = 0.f, ay = 0.f;                     // lane owns ch 2*lane, 2*lane+1

    for (int jj = 0; jj < d; jj += 64) {          // 64 edges per idx load
        int s_all = ssrc[beg + jj + lane];        // coalesced; span padded-32
        int jend = d - jj; if (jend > 64) jend = 64;
#pragma unroll
        for (int b = 0; b < 2; b++) {
            if (b * 32 < jend) {                  // wave-uniform (d uniform)
                unsigned vv[32];
#pragma unroll
                for (int u = 0; u < 32; u++) {
                    int su = __builtin_amdgcn_readlane(s_all, b * 32 + u);
                    vv[u] = *(const unsigned*)(Hb + (size_t)su * 256 + lane * 4);
                }
#pragma unroll
                for (int u = 0; u < 32; u++) {
                    float2 f = __half22float2(*(const __half2*)&vv[u]);
                    ax += f.x; ay += f.y;
                }
            }
        }
    }

    // epilogue: self-loop + bias + relu, per-lane channel pair — no shuffle
    float2 sf = __half22float2(((const __half2*)(Hb + (size_t)node * 256))[lane]);
    float2 bb = ((const float2*)bias)[lane];
    float2 o;
    o.x = fmaxf(fmaf(di, ax + sf.x, bb.x), 0.f);
    o.y = fmaxf(fmaf(di, ay + sf.y, bb.y), 0.f);
    *(float2*)&x2buf[wave][2 * lane] = o;
    __syncthreads();

    // GEMM phase: waves 0-3, wave = col-frag c (16 cols each)
    if (threadIdx.x < 256) {
        int c = wave;
        int q = lane >> 4, lr = lane & 15;
        f32x4 g = (f32x4){0.f, 0.f, 0.f, 0.f};
#pragma unroll
        for (int s = 0; s < 4; s++) {
            const float* xp = &x2buf[lr][s * 32 + q * 8];
            float4 a0 = *(const float4*)xp;
            float4 a1 = *(const float4*)(xp + 4);
            float xv[8] = {a0.x, a0.y, a0.z, a0.w, a1.x, a1.y, a1.z, a1.w};
            bf16x8 a_hi, a_lo;
#pragma unroll
            for (int j = 0; j < 8; j++) {
                __bf16 h = (__bf16)xv[j];
                a_hi[j] = h;
                a_lo[j] = (__bf16)(xv[j] - (float)h);
            }
            size_t fo = (size_t)((c * 4 + s) * 64 + lane) * 8;
            bf16x8 bh = *(const bf16x8*)(w2hi + fo);
            bf16x8 bl = *(const bf16x8*)(w2lo + fo);
            g = __builtin_amdgcn_mfma_f32_16x16x32_bf16(a_hi, bh, g, 0, 0, 0);
            g = __builtin_amdgcn_mfma_f32_16x16x32_bf16(a_lo, bh, g, 0, 0, 0);
            g = __builtin_amdgcn_mfma_f32_16x16x32_bf16(a_hi, bl, g, 0, 0, 0);
        }
#pragma unroll
        for (int r = 0; r < 4; r++) {
            int grow = rb + q * 4 + r;
            hs2[(size_t)grow * 64 + c * 16 + lr] = __float2half(g[r] * dinv[grow]);
        }
    }
}

// ---------------- Aggregate CH=64: wave/node, uniform-row whole-wave gathers ------
// R16: s_all + readlane -> scalar-base row reads, lane = channel (ushort),
// no shuffle reduction. One idx roundtrip + one 32-deep burst per node.
__global__ __launch_bounds__(256) void aggregate64_kernel(
        const __half* __restrict__ hs, const int* __restrict__ row_off,
        const int* __restrict__ deg, const int* __restrict__ ssrc,
        const float* __restrict__ dinv, const float* __restrict__ bias,
        float* __restrict__ out) {
    int node = (blockIdx.x * 256 + threadIdx.x) >> 6;
    int lane = threadIdx.x & 63;
    if (node >= N_NODES) return;
    int beg = __builtin_amdgcn_readfirstlane(row_off[node]);
    int d   = __builtin_amdgcn_readfirstlane(deg[node]);
    float di = dinv[node];
    const char* Hb = (const char*)hs;             // row stride 128B
    float acc = 0.f;                              // lane owns channel `lane`

    for (int jj = 0; jj < d; jj += 64) {
        int s_all = ssrc[beg + jj + lane];
        int jend = d - jj; if (jend > 64) jend = 64;
#pragma unroll
        for (int b = 0; b < 2; b++) {
            if (b * 32 < jend) {
                unsigned short vv[32];
#pragma unroll
                for (int u = 0; u < 32; u++) {
                    int su = __builtin_amdgcn_readlane(s_all, b * 32 + u);
                    vv[u] = *(const unsigned short*)(Hb + (size_t)su * 128 + lane * 2);
                }
#pragma unroll
                for (int u = 0; u < 32; u++) {
                    acc += __half2float(*(const __half*)&vv[u]);
                }
            }
        }
    }

    float sf = __half2float(((const __half*)(Hb + (size_t)node * 128))[lane]);
    out[(size_t)node * 64 + lane] = fmaf(di, acc + sf, bias[lane]);
}

// ---------------- launch ----------------

extern "C" void kernel_launch(void* const* d_in, const int* in_sizes, int n_in,
                              void* d_out, int out_size, void* d_ws, size_t ws_size,
                              hipStream_t stream) {
    const float* x  = (const float*)d_in[0];   // [N,128]
    const int*   ei = (const int*)d_in[1];     // [2,E]
    const float* W1 = (const float*)d_in[2];   // [128,128]
    const float* b1 = (const float*)d_in[3];   // [128]
    const float* W2 = (const float*)d_in[4];   // [128,64]
    const float* b2 = (const float*)d_in[5];   // [64]
    float* out = (float*)d_out;                // [N,64]

    const int* src = ei;
    const int* dst = ei + N_EDGES;

    char* p = (char*)d_ws;
    size_t off = 0;
    auto alloc = [&](size_t bytes) { void* q = p + off; off += (bytes + 255) & ~(size_t)255; return q; };
    float*    dinv    = (float*)   alloc(N_NODES * 4);
    int*      deg     = (int*)     alloc(N_NODES * 4);
    int*      row_off = (int*)     alloc(N_NODES * 4);
    int*      gcur    = (int*)     alloc(NBIN * 4);
    int*      ssrc    = (int*)     alloc((size_t)NBIN * CAP2 * 4);  // 10.4 MB
    unsigned* ebin    = (unsigned*)alloc((size_t)NBIN * CAP * 4);   // 4.0 MB
    __bf16*   w1hi    = (__bf16*)  alloc(128 * 128 * 2);
    __bf16*   w1lo    = (__bf16*)  alloc(128 * 128 * 2);
    __bf16*   w2hi    = (__bf16*)  alloc(128 * 64 * 2);
    __bf16*   w2lo    = (__bf16*)  alloc(128 * 64 * 2);
    __half*   hs1     = (__half*)  alloc((size_t)(N_NODES + 1) * 128 * 2);
    __half*   hs2     = (__half*)  alloc((size_t)(N_NODES + 1) * 64 * 2);

    // 6 launches total
    prep_kernel<<<13, 256, 0, stream>>>(W1, W2, w1hi, w1lo, w2hi, w2lo, gcur, hs1, hs2);
    bin_scatter_kernel<<<NB_SCAT, 256, 0, stream>>>(src, dst, gcur, ebin);
    bin_build_kernel<<<NBIN, 256, 0, stream>>>(ebin, gcur, deg, row_off, dinv, ssrc);

    gemm_mfma128_kernel<<<(N_NODES + 63) / 64, 256, 0, stream>>>(x, w1hi, w1lo, dinv, hs1);
    fused_agg_gemm_kernel<<<N_NODES / 16, 1024, 0, stream>>>(
        hs1, row_off, deg, ssrc, dinv, b1, w2hi, w2lo, hs2);
    aggregate64_kernel<<<(N_NODES * 64 + 255) / 256, 256, 0, stream>>>(
        hs2, row_off, deg, ssrc, dinv, b2, out);
}